// Round 8
// baseline (151.125 us; speedup 1.0000x reference)
//
#include <hip/hip_runtime.h>
#include <math.h>

#define NW   64      // windows (B_)
#define NTOK 256     // tokens per window (N)
#define CDIM 128     // channels (C)
#define NH   4       // heads (H)
#define HD   32      // head dim
#define TKIN 64      // incoming topk
#define TKOUT 32     // outgoing topk

static __device__ __forceinline__ float wave_max64f(float x) {
  #pragma unroll
  for (int off = 32; off >= 1; off >>= 1) x = fmaxf(x, __shfl_xor(x, off));
  return x;
}

// Classic Cephes expf exactly as in sse_mathfun / Eigen pexp<float> (SSE2,
// no FMA): every op individually rounded f32. Matches the np reference's
// exp bit patterns (verified round 6). DO NOT TOUCH.
static __device__ __forceinline__ float cephes_expf(float x) {
  x = fminf(x, 88.3762626647949f);
  x = fmaxf(x, -88.3762626647949f);
  float fx = __fadd_rn(__fmul_rn(x, 1.44269504088896341f), 0.5f);
  fx = floorf(fx);
  float tmp = __fmul_rn(fx, 0.693359375f);
  float z2  = __fmul_rn(fx, -2.12194440e-4f);
  x = __fsub_rn(x, tmp);
  x = __fsub_rn(x, z2);
  float z = __fmul_rn(x, x);
  float y = 1.9875691500E-4f;
  y = __fadd_rn(__fmul_rn(y, x), 1.3981999507E-3f);
  y = __fadd_rn(__fmul_rn(y, x), 8.3334519073E-3f);
  y = __fadd_rn(__fmul_rn(y, x), 4.1665795894E-2f);
  y = __fadd_rn(__fmul_rn(y, x), 1.6666665459E-1f);
  y = __fadd_rn(__fmul_rn(y, x), 5.0000001201E-1f);
  y = __fadd_rn(__fmul_rn(y, z), x);
  y = __fadd_rn(y, 1.0f);
  int n = __float2int_rz(fx);              // fx is integral
  float p2n = __int_as_float((n + 127) << 23);
  return __fmul_rn(y, p2n);
}

// numpy pairwise_sum structure for n=64 (unrolled-by-8 C loop); row-uniform
// by commutativity. Verified round 6. DO NOT TOUCH.
static __device__ __forceinline__ float np_pairwise_sum64(float x, int lane) {
  int k = lane & 7;
  float r = __shfl(x, k);
  #pragma unroll
  for (int i2 = 1; i2 < 8; ++i2) r = __fadd_rn(r, __shfl(x, k + 8 * i2));
  float u = __fadd_rn(r, __shfl_xor(r, 1));
  float v = __fadd_rn(u, __shfl_xor(u, 2));
  float w = __fadd_rn(v, __shfl_xor(v, 4));
  return w;
}

// Kernel 1: one block per (window, head, half). 512 threads = 8 waves; each
// wave owns 16 consecutive query rows, NO per-row block barriers (a_buf /
// sel_* strictly per-wave). Only K is LDS-staged (per-lane random-row
// gather); V rows are wave-uniform reads -> served from global via L1/L2.
// LDS ~38 KB -> 4 blocks/CU -> 32 waves/CU (occupancy cap), enforced by
// __launch_bounds__(512, 8) (VGPR <= 64; was 56).
__global__ __launch_bounds__(512, 8) void attn_topk_kernel(
    const float* __restrict__ qkvp,        // [NW, NTOK, 4*CDIM]
    const float* __restrict__ pfa_values,  // [NW, NH, NTOK, TKIN]
    const int*   __restrict__ pfa_indices, // [NW, NH, NTOK, TKIN]
    const int*   __restrict__ rpi,         // [NTOK, NTOK]
    const float* __restrict__ bias_table,  // [961, NH]
    float* __restrict__ xattn,             // [NW*NTOK, CDIM] (pre-projection, = out region)
    float* __restrict__ vals_out,          // [NW, NH, NTOK, TKOUT]
    float* __restrict__ idx_out)           // [NW, NH, NTOK, TKOUT] (as floats)
{
  __shared__ float k_s[NTOK * 33];         // stride 33: bank = (tok+d)%32
  __shared__ __align__(16) float a_buf[8 * 64];   // per-wave rank buffer
  __shared__ float sel_val[8 * 32];        // per-wave selected values
  __shared__ int   sel_idx[8 * 32];

  const int bx    = blockIdx.x;            // 0..511
  const int b     = bx >> 3;
  const int h     = (bx >> 1) & 3;
  const int qhalf = bx & 1;
  const int tid   = threadIdx.x;
  const int lane  = tid & 63;
  const int wid   = tid >> 6;              // 0..7

  const float SCALE_F = 0.17677669529663687f;  // fl32(32^-0.5)
  const float EPS_F   = 1e-10f;

  const float* qbase = qkvp + (size_t)b * (NTOK * 4 * CDIM);
  const float* vglob = qbase + 256 + h * 32;     // part 2, this head

  // Stage K (part 1) for this (b,h): 256 tokens x 32 dims.
  #pragma unroll 4
  for (int l = 0; l < 16; ++l) {
    int e   = l * 512 + tid;
    int tok = e >> 5, d = e & 31;
    k_s[tok * 33 + d] = qbase[tok * 512 + 128 + h * 32 + d];
  }
  __syncthreads();

  const int i0 = qhalf * 128 + wid * 16;   // this wave's first row
  const size_t rowbase = (size_t)((b * NH + h) * NTOK + i0);
  const int*   idx_p = pfa_indices + rowbase * TKIN + lane;
  const float* val_p = pfa_values  + rowbase * TKIN + lane;

  int   kidx = idx_p[0];
  float pv   = val_p[0];

  for (int r = 0; r < 16; ++r) {
    const int i = i0 + r;
    const size_t rowoff = rowbase + r;

    // Issue the dependent gather chain + next-row prefetch ASAP; the dot
    // below (LDS-only) overlaps their latency.
    const int rpi_c = rpi[i * NTOK + kidx];
    int   kidx_n = 0;
    float pv_n   = 0.0f;
    if (r < 15) { kidx_n = idx_p[(r + 1) * TKIN]; pv_n = val_p[(r + 1) * TKIN]; }
    const float lepe = qbase[i * 512 + 384 + h * 32 + (lane & 31)];

    // QK dot: 4 accumulators (d mod 4), separate mul/add, movehl finalize.
    // Bit-exact np einsum emulation. DO NOT TOUCH.
    const float* qrow = qbase + i * 512 + h * 32;   // part 0
    const float* krow = &k_s[kidx * 33];
    float acc0 = 0.0f, acc1 = 0.0f, acc2 = 0.0f, acc3 = 0.0f;
    #pragma unroll
    for (int i4 = 0; i4 < 8; ++i4) {
      float4 q4 = ((const float4*)qrow)[i4];
      acc0 = __fadd_rn(acc0, __fmul_rn(__fmul_rn(q4.x, SCALE_F), krow[i4 * 4 + 0]));
      acc1 = __fadd_rn(acc1, __fmul_rn(__fmul_rn(q4.y, SCALE_F), krow[i4 * 4 + 1]));
      acc2 = __fadd_rn(acc2, __fmul_rn(__fmul_rn(q4.z, SCALE_F), krow[i4 * 4 + 2]));
      acc3 = __fadd_rn(acc3, __fmul_rn(__fmul_rn(q4.w, SCALE_F), krow[i4 * 4 + 3]));
    }
    const float bias = bias_table[rpi_c * NH + h];
    const float dot  = __fadd_rn(__fadd_rn(acc0, acc2), __fadd_rn(acc1, acc3));
    const float s    = __fadd_rn(dot, bias);

    // softmax over the 64 keys (one per lane); np-structured sums
    float m  = wave_max64f(s);
    float ex = cephes_expf(__fsub_rn(s, m));
    float sm = np_pairwise_sum64(ex, lane);
    float p0 = __fdiv_rn(ex, sm);
    float a  = __fmul_rn(p0, pv);              // modulate by prior values
    float s2 = np_pairwise_sum64(a, lane);
    float af = __fdiv_rn(__fadd_rn(a, EPS_F), __fadd_rn(s2, EPS_F));

    // stable descending rank (ties -> lower slot first); per-wave buffer,
    // in-wave LDS ordering needs no barrier. float4 broadcast reads.
    a_buf[wid * 64 + lane] = af;
    int rank = 0;
    const float4* ab4 = (const float4*)&a_buf[wid * 64];
    #pragma unroll
    for (int j4 = 0; j4 < 16; ++j4) {
      float4 v4 = ab4[j4];
      int j = j4 * 4;
      rank += (v4.x > af || (v4.x == af && (j + 0) < lane)) ? 1 : 0;
      rank += (v4.y > af || (v4.y == af && (j + 1) < lane)) ? 1 : 0;
      rank += (v4.z > af || (v4.z == af && (j + 2) < lane)) ? 1 : 0;
      rank += (v4.w > af || (v4.w == af && (j + 3) < lane)) ? 1 : 0;
    }

    if (rank < TKOUT) {
      sel_val[wid * 32 + rank] = af;
      sel_idx[wid * 32 + rank] = kidx;
      vals_out[rowoff * TKOUT + rank] = af;
      idx_out [rowoff * TKOUT + rank] = (float)kidx;
    }

    // AV: lanes (ph,d); V rows read from global (wave-uniform row ->
    // coalesced 128B per half-wave, L1/L2-resident slice).
    const int ph = lane >> 5, d = lane & 31;
    float oacc = 0.0f;
    #pragma unroll 2
    for (int t2 = 0; t2 < 16; ++t2) {
      int   tt = ph * 16 + t2;
      float vv = sel_val[wid * 32 + tt];   // broadcast
      int   ix = sel_idx[wid * 32 + tt];   // broadcast
      oacc += vv * vglob[(size_t)ix * 512 + d];
    }
    oacc += __shfl_xor(oacc, 32);
    if (ph == 0) {
      xattn[(size_t)(b * NTOK + i) * CDIM + h * 32 + d] = oacc + lepe;
    }

    kidx = kidx_n;
    pv   = pv_n;
  }
}

// Kernel 2: in-place projection out = x @ W^T + b over 16 rows per block.
// Each block stages exactly its own 16 rows before overwriting them.
__global__ __launch_bounds__(256) void proj_kernel(
    float* __restrict__ x_out,            // [NW*NTOK, CDIM], read then overwritten
    const float* __restrict__ proj_w,     // [CDIM, CDIM]  (out_c, in_c)
    const float* __restrict__ proj_b)     // [CDIM]
{
  __shared__ __align__(16) float w_t[CDIM * 132];   // w_t[ic][oc], stride 132
  __shared__ __align__(16) float x_s[16 * CDIM];

  const int tid = threadIdx.x;
  const int rowbase = blockIdx.x * 16;

  #pragma unroll 8
  for (int l = 0; l < 64; ++l) {
    int e  = l * 256 + tid;
    int oc = e >> 7, ic = e & 127;
    w_t[ic * 132 + oc] = proj_w[e];
  }
  #pragma unroll
  for (int l = 0; l < 8; ++l) {
    int e = l * 256 + tid;
    x_s[e] = x_out[(size_t)rowbase * CDIM + e];
  }
  __syncthreads();

  const int c0 = tid & 31;   // column group (4 cols)
  const int rs = tid >> 5;   // row slot (rows rs and rs+8)

  float acc0x = 0, acc0y = 0, acc0z = 0, acc0w = 0;
  float acc1x = 0, acc1y = 0, acc1z = 0, acc1w = 0;

  for (int cc4 = 0; cc4 < 32; ++cc4) {
    float4 x0 = *(const float4*)&x_s[rs * CDIM + cc4 * 4];
    float4 x1 = *(const float4*)&x_s[(rs + 8) * CDIM + cc4 * 4];
    const float xs0[4] = {x0.x, x0.y, x0.z, x0.w};
    const float xs1[4] = {x1.x, x1.y, x1.z, x1.w};
    #pragma unroll
    for (int u = 0; u < 4; ++u) {
      int cc = cc4 * 4 + u;
      float4 w4 = *(const float4*)&w_t[cc * 132 + c0 * 4];
      acc0x += xs0[u] * w4.x;  acc0y += xs0[u] * w4.y;
      acc0z += xs0[u] * w4.z;  acc0w += xs0[u] * w4.w;
      acc1x += xs1[u] * w4.x;  acc1y += xs1[u] * w4.y;
      acc1z += xs1[u] * w4.z;  acc1w += xs1[u] * w4.w;
    }
  }

  float4 bb = *(const float4*)&proj_b[c0 * 4];
  float4 o0 = make_float4(acc0x + bb.x, acc0y + bb.y, acc0z + bb.z, acc0w + bb.w);
  float4 o1 = make_float4(acc1x + bb.x, acc1y + bb.y, acc1z + bb.z, acc1w + bb.w);
  *(float4*)&x_out[(size_t)(rowbase + rs) * CDIM + c0 * 4] = o0;
  *(float4*)&x_out[(size_t)(rowbase + rs + 8) * CDIM + c0 * 4] = o1;
}

extern "C" void kernel_launch(void* const* d_in, const int* in_sizes, int n_in,
                              void* d_out, int out_size, void* d_ws, size_t ws_size,
                              hipStream_t stream) {
  (void)in_sizes; (void)n_in; (void)d_ws; (void)ws_size; (void)out_size;

  const float* qkvp        = (const float*)d_in[0];
  const float* pfa_values  = (const float*)d_in[1];
  const int*   pfa_indices = (const int*)  d_in[2];
  const int*   rpi         = (const int*)  d_in[3];
  const float* bias_table  = (const float*)d_in[4];
  const float* proj_w      = (const float*)d_in[5];
  const float* proj_b      = (const float*)d_in[6];

  float* out      = (float*)d_out;                       // [NW*NTOK, CDIM]
  float* vals_out = out + (size_t)NW * NTOK * CDIM;      // [NW,NH,NTOK,TKOUT]
  float* idx_out  = vals_out + (size_t)NW * NH * NTOK * TKOUT;

  // Kernel 1 writes pre-projection xattn into the `out` region (same size),
  // plus vals/new_idx. Kernel 2 projects in place.
  attn_topk_kernel<<<NW * NH * 2, 512, 0, stream>>>(
      qkvp, pfa_values, pfa_indices, rpi, bias_table, out, vals_out, idx_out);
  proj_kernel<<<(NW * NTOK) / 16, 256, 0, stream>>>(out, proj_w, proj_b);
}

// Round 9
// 101.580 us; speedup vs baseline: 1.4877x; 1.4877x over previous
//
#include <hip/hip_runtime.h>
#include <math.h>

#define NW   64      // windows (B_)
#define NTOK 256     // tokens per window (N)
#define CDIM 128     // channels (C)
#define NH   4       // heads (H)
#define HD   32      // head dim
#define TKIN 64      // incoming topk
#define TKOUT 32     // outgoing topk

static __device__ __forceinline__ float wave_max64f(float x) {
  #pragma unroll
  for (int off = 32; off >= 1; off >>= 1) x = fmaxf(x, __shfl_xor(x, off));
  return x;
}

// Classic Cephes expf exactly as in sse_mathfun / Eigen pexp<float> (SSE2,
// no FMA): every op individually rounded f32. Matches the np reference's
// exp bit patterns (verified round 6). DO NOT TOUCH.
static __device__ __forceinline__ float cephes_expf(float x) {
  x = fminf(x, 88.3762626647949f);
  x = fmaxf(x, -88.3762626647949f);
  float fx = __fadd_rn(__fmul_rn(x, 1.44269504088896341f), 0.5f);
  fx = floorf(fx);
  float tmp = __fmul_rn(fx, 0.693359375f);
  float z2  = __fmul_rn(fx, -2.12194440e-4f);
  x = __fsub_rn(x, tmp);
  x = __fsub_rn(x, z2);
  float z = __fmul_rn(x, x);
  float y = 1.9875691500E-4f;
  y = __fadd_rn(__fmul_rn(y, x), 1.3981999507E-3f);
  y = __fadd_rn(__fmul_rn(y, x), 8.3334519073E-3f);
  y = __fadd_rn(__fmul_rn(y, x), 4.1665795894E-2f);
  y = __fadd_rn(__fmul_rn(y, x), 1.6666665459E-1f);
  y = __fadd_rn(__fmul_rn(y, x), 5.0000001201E-1f);
  y = __fadd_rn(__fmul_rn(y, z), x);
  y = __fadd_rn(y, 1.0f);
  int n = __float2int_rz(fx);              // fx is integral
  float p2n = __int_as_float((n + 127) << 23);
  return __fmul_rn(y, p2n);
}

// numpy pairwise_sum structure for n=64 (unrolled-by-8 C loop); row-uniform
// by commutativity. Verified round 6. DO NOT TOUCH.
static __device__ __forceinline__ float np_pairwise_sum64(float x, int lane) {
  int k = lane & 7;
  float r = __shfl(x, k);
  #pragma unroll
  for (int i2 = 1; i2 < 8; ++i2) r = __fadd_rn(r, __shfl(x, k + 8 * i2));
  float u = __fadd_rn(r, __shfl_xor(r, 1));
  float v = __fadd_rn(u, __shfl_xor(u, 2));
  float w = __fadd_rn(v, __shfl_xor(v, 4));
  return w;
}

// Kernel 1: one block per (window, head, half). 512 threads = 8 waves; each
// wave owns 16 consecutive query rows, NO per-row block barriers (a_buf /
// sel_* strictly per-wave). K and V staged in LDS (round-7 structure).
// All global inputs software-pipelined ONE ROW AHEAD:
//   kidx,pv (independent) -> rpi[i,kidx] (dep) -> bias_table[rpi] (dep)
//   plus the 8x float4 q-row. The 2-chained-gather bias path gets a full
//   row body (~1000 cyc) of slack instead of stalling after the dot.
// __launch_bounds__(512,4): VGPR <= 128 = 4 waves/SIMD = the 2-block/CU
// LDS cap -> VGPR non-binding (round-8 lesson: never squeeze below need).
__global__ __launch_bounds__(512, 4) void attn_topk_kernel(
    const float* __restrict__ qkvp,        // [NW, NTOK, 4*CDIM]
    const float* __restrict__ pfa_values,  // [NW, NH, NTOK, TKIN]
    const int*   __restrict__ pfa_indices, // [NW, NH, NTOK, TKIN]
    const int*   __restrict__ rpi,         // [NTOK, NTOK]
    const float* __restrict__ bias_table,  // [961, NH]
    float* __restrict__ xattn,             // [NW*NTOK, CDIM] (pre-projection, = out region)
    float* __restrict__ vals_out,          // [NW, NH, NTOK, TKOUT]
    float* __restrict__ idx_out)           // [NW, NH, NTOK, TKOUT] (as floats)
{
  __shared__ float k_s[NTOK * 33];         // stride 33: bank = (tok+d)%32
  __shared__ float v_s[NTOK * 33];
  __shared__ __align__(16) float a_buf[8 * 64];   // per-wave rank buffer
  __shared__ float sel_val[8 * 32];        // per-wave selected values
  __shared__ int   sel_idx[8 * 32];

  const int bx    = blockIdx.x;            // 0..511
  const int b     = bx >> 3;
  const int h     = (bx >> 1) & 3;
  const int qhalf = bx & 1;
  const int tid   = threadIdx.x;
  const int lane  = tid & 63;
  const int wid   = tid >> 6;              // 0..7

  const float SCALE_F = 0.17677669529663687f;  // fl32(32^-0.5)
  const float EPS_F   = 1e-10f;

  const float* qbase = qkvp + (size_t)b * (NTOK * 4 * CDIM);

  // Stage K (part 1) and V (part 2) for this (b,h): 256 tokens x 32 dims.
  #pragma unroll 4
  for (int l = 0; l < 16; ++l) {
    int e   = l * 512 + tid;
    int tok = e >> 5, d = e & 31;
    int g   = tok * 512 + h * 32 + d;
    k_s[tok * 33 + d] = qbase[g + 128];
    v_s[tok * 33 + d] = qbase[g + 256];
  }
  __syncthreads();

  const int i0 = qhalf * 128 + wid * 16;   // this wave's first row
  const size_t rowbase = (size_t)((b * NH + h) * NTOK + i0);
  const int*   idx_p = pfa_indices + rowbase * TKIN + lane;
  const float* val_p = pfa_values  + rowbase * TKIN + lane;

  // Prologue: row 0 inputs (full chain + q row)
  int   kidx  = idx_p[0];
  float pv    = val_p[0];
  int   rpi_c = rpi[i0 * NTOK + kidx];
  float bias  = bias_table[rpi_c * NH + h];
  float4 qv[8];
  #pragma unroll
  for (int u = 0; u < 8; ++u)
    qv[u] = ((const float4*)(qbase + i0 * 512 + h * 32))[u];

  for (int r = 0; r < 16; ++r) {
    const int i = i0 + r;
    const size_t rowoff = rowbase + r;
    const int rn  = (r < 15) ? r + 1 : 15;     // clamped prefetch row
    const int in_ = i0 + rn;

    // ---- next-row prefetch: independents first, then the dependent chain
    const int   kidx_n = idx_p[rn * TKIN];
    const float pv_n   = val_p[rn * TKIN];
    float4 qn[8];
    #pragma unroll
    for (int u = 0; u < 8; ++u)
      qn[u] = ((const float4*)(qbase + in_ * 512 + h * 32))[u];
    const int rpi_n = rpi[in_ * NTOK + kidx_n];      // waits only on kidx_n

    // lepe for THIS row (used at the very end -> plenty of slack)
    const float lepe = qbase[i * 512 + 384 + h * 32 + (lane & 31)];

    // QK dot: 4 accumulators (d mod 4), separate mul/add, movehl finalize.
    // Bit-exact np einsum emulation. DO NOT TOUCH.
    const float* krow = &k_s[kidx * 33];
    float acc0 = 0.0f, acc1 = 0.0f, acc2 = 0.0f, acc3 = 0.0f;
    #pragma unroll
    for (int i4 = 0; i4 < 8; ++i4) {
      acc0 = __fadd_rn(acc0, __fmul_rn(__fmul_rn(qv[i4].x, SCALE_F), krow[i4 * 4 + 0]));
      acc1 = __fadd_rn(acc1, __fmul_rn(__fmul_rn(qv[i4].y, SCALE_F), krow[i4 * 4 + 1]));
      acc2 = __fadd_rn(acc2, __fmul_rn(__fmul_rn(qv[i4].z, SCALE_F), krow[i4 * 4 + 2]));
      acc3 = __fadd_rn(acc3, __fmul_rn(__fmul_rn(qv[i4].w, SCALE_F), krow[i4 * 4 + 3]));
    }
    const float dot = __fadd_rn(__fadd_rn(acc0, acc2), __fadd_rn(acc1, acc3));
    const float s   = __fadd_rn(dot, bias);

    // issue next row's bias gather now (waits only on rpi_n; used next row)
    const float bias_n = bias_table[rpi_n * NH + h];

    // softmax over the 64 keys (one per lane); np-structured sums
    float m  = wave_max64f(s);
    float ex = cephes_expf(__fsub_rn(s, m));
    float sm = np_pairwise_sum64(ex, lane);
    float p0 = __fdiv_rn(ex, sm);
    float a  = __fmul_rn(p0, pv);              // modulate by prior values
    float s2 = np_pairwise_sum64(a, lane);
    float af = __fdiv_rn(__fadd_rn(a, EPS_F), __fadd_rn(s2, EPS_F));

    // stable descending rank (ties -> lower slot first); per-wave buffer,
    // in-wave LDS ordering needs no barrier. float4 broadcast reads.
    a_buf[wid * 64 + lane] = af;
    int rank = 0;
    const float4* ab4 = (const float4*)&a_buf[wid * 64];
    #pragma unroll
    for (int j4 = 0; j4 < 16; ++j4) {
      float4 v4 = ab4[j4];
      int j = j4 * 4;
      rank += (v4.x > af || (v4.x == af && (j + 0) < lane)) ? 1 : 0;
      rank += (v4.y > af || (v4.y == af && (j + 1) < lane)) ? 1 : 0;
      rank += (v4.z > af || (v4.z == af && (j + 2) < lane)) ? 1 : 0;
      rank += (v4.w > af || (v4.w == af && (j + 3) < lane)) ? 1 : 0;
    }

    if (rank < TKOUT) {
      sel_val[wid * 32 + rank] = af;
      sel_idx[wid * 32 + rank] = kidx;
      vals_out[rowoff * TKOUT + rank] = af;
      idx_out [rowoff * TKOUT + rank] = (float)kidx;
    }

    // AV: lanes (ph,d); ranks are a permutation so all 32 slots are fresh.
    const int ph = lane >> 5, d = lane & 31;
    float oacc = 0.0f;
    #pragma unroll
    for (int t2 = 0; t2 < 16; ++t2) {
      int   tt = ph * 16 + t2;
      float vv = sel_val[wid * 32 + tt];   // broadcast
      int   ix = sel_idx[wid * 32 + tt];   // broadcast
      oacc += vv * v_s[ix * 33 + d];       // banks spread over d
    }
    oacc += __shfl_xor(oacc, 32);
    if (ph == 0) {
      xattn[(size_t)(b * NTOK + i) * CDIM + h * 32 + d] = oacc + lepe;
    }

    // rotate pipeline registers
    kidx = kidx_n;  pv = pv_n;  bias = bias_n;
    #pragma unroll
    for (int u = 0; u < 8; ++u) qv[u] = qn[u];
  }
}

// Kernel 2: in-place projection out = x @ W^T + b over 16 rows per block.
// Each block stages exactly its own 16 rows before overwriting them.
__global__ __launch_bounds__(256) void proj_kernel(
    float* __restrict__ x_out,            // [NW*NTOK, CDIM], read then overwritten
    const float* __restrict__ proj_w,     // [CDIM, CDIM]  (out_c, in_c)
    const float* __restrict__ proj_b)     // [CDIM]
{
  __shared__ __align__(16) float w_t[CDIM * 132];   // w_t[ic][oc], stride 132
  __shared__ __align__(16) float x_s[16 * CDIM];

  const int tid = threadIdx.x;
  const int rowbase = blockIdx.x * 16;

  #pragma unroll 8
  for (int l = 0; l < 64; ++l) {
    int e  = l * 256 + tid;
    int oc = e >> 7, ic = e & 127;
    w_t[ic * 132 + oc] = proj_w[e];
  }
  #pragma unroll
  for (int l = 0; l < 8; ++l) {
    int e = l * 256 + tid;
    x_s[e] = x_out[(size_t)rowbase * CDIM + e];
  }
  __syncthreads();

  const int c0 = tid & 31;   // column group (4 cols)
  const int rs = tid >> 5;   // row slot (rows rs and rs+8)

  float acc0x = 0, acc0y = 0, acc0z = 0, acc0w = 0;
  float acc1x = 0, acc1y = 0, acc1z = 0, acc1w = 0;

  for (int cc4 = 0; cc4 < 32; ++cc4) {
    float4 x0 = *(const float4*)&x_s[rs * CDIM + cc4 * 4];
    float4 x1 = *(const float4*)&x_s[(rs + 8) * CDIM + cc4 * 4];
    const float xs0[4] = {x0.x, x0.y, x0.z, x0.w};
    const float xs1[4] = {x1.x, x1.y, x1.z, x1.w};
    #pragma unroll
    for (int u = 0; u < 4; ++u) {
      int cc = cc4 * 4 + u;
      float4 w4 = *(const float4*)&w_t[cc * 132 + c0 * 4];
      acc0x += xs0[u] * w4.x;  acc0y += xs0[u] * w4.y;
      acc0z += xs0[u] * w4.z;  acc0w += xs0[u] * w4.w;
      acc1x += xs1[u] * w4.x;  acc1y += xs1[u] * w4.y;
      acc1z += xs1[u] * w4.z;  acc1w += xs1[u] * w4.w;
    }
  }

  float4 bb = *(const float4*)&proj_b[c0 * 4];
  float4 o0 = make_float4(acc0x + bb.x, acc0y + bb.y, acc0z + bb.z, acc0w + bb.w);
  float4 o1 = make_float4(acc1x + bb.x, acc1y + bb.y, acc1z + bb.z, acc1w + bb.w);
  *(float4*)&x_out[(size_t)(rowbase + rs) * CDIM + c0 * 4] = o0;
  *(float4*)&x_out[(size_t)(rowbase + rs + 8) * CDIM + c0 * 4] = o1;
}

extern "C" void kernel_launch(void* const* d_in, const int* in_sizes, int n_in,
                              void* d_out, int out_size, void* d_ws, size_t ws_size,
                              hipStream_t stream) {
  (void)in_sizes; (void)n_in; (void)d_ws; (void)ws_size; (void)out_size;

  const float* qkvp        = (const float*)d_in[0];
  const float* pfa_values  = (const float*)d_in[1];
  const int*   pfa_indices = (const int*)  d_in[2];
  const int*   rpi         = (const int*)  d_in[3];
  const float* bias_table  = (const float*)d_in[4];
  const float* proj_w      = (const float*)d_in[5];
  const float* proj_b      = (const float*)d_in[6];

  float* out      = (float*)d_out;                       // [NW*NTOK, CDIM]
  float* vals_out = out + (size_t)NW * NTOK * CDIM;      // [NW,NH,NTOK,TKOUT]
  float* idx_out  = vals_out + (size_t)NW * NH * NTOK * TKOUT;

  // Kernel 1 writes pre-projection xattn into the `out` region (same size),
  // plus vals/new_idx. Kernel 2 projects in place.
  attn_topk_kernel<<<NW * NH * 2, 512, 0, stream>>>(
      qkvp, pfa_values, pfa_indices, rpi, bias_table, out, vals_out, idx_out);
  proj_kernel<<<(NW * NTOK) / 16, 256, 0, stream>>>(out, proj_w, proj_b);
}

// Round 10
// 97.711 us; speedup vs baseline: 1.5467x; 1.0396x over previous
//
#include <hip/hip_runtime.h>
#include <math.h>

#define NW   64      // windows (B_)
#define NTOK 256     // tokens per window (N)
#define CDIM 128     // channels (C)
#define NH   4       // heads (H)
#define HD   32      // head dim
#define TKIN 64      // incoming topk
#define TKOUT 32     // outgoing topk
#define KSTR 34      // K/V LDS row stride (even -> 8B-aligned rows for b64)

typedef float f32x2 __attribute__((ext_vector_type(2)));

static __device__ __forceinline__ float wave_max64f(float x) {
  #pragma unroll
  for (int off = 32; off >= 1; off >>= 1) x = fmaxf(x, __shfl_xor(x, off));
  return x;
}

// Classic Cephes expf exactly as in sse_mathfun / Eigen pexp<float> (SSE2,
// no FMA): every op individually rounded f32. Matches the np reference's
// exp bit patterns (verified round 6). DO NOT TOUCH.
static __device__ __forceinline__ float cephes_expf(float x) {
  x = fminf(x, 88.3762626647949f);
  x = fmaxf(x, -88.3762626647949f);
  float fx = __fadd_rn(__fmul_rn(x, 1.44269504088896341f), 0.5f);
  fx = floorf(fx);
  float tmp = __fmul_rn(fx, 0.693359375f);
  float z2  = __fmul_rn(fx, -2.12194440e-4f);
  x = __fsub_rn(x, tmp);
  x = __fsub_rn(x, z2);
  float z = __fmul_rn(x, x);
  float y = 1.9875691500E-4f;
  y = __fadd_rn(__fmul_rn(y, x), 1.3981999507E-3f);
  y = __fadd_rn(__fmul_rn(y, x), 8.3334519073E-3f);
  y = __fadd_rn(__fmul_rn(y, x), 4.1665795894E-2f);
  y = __fadd_rn(__fmul_rn(y, x), 1.6666665459E-1f);
  y = __fadd_rn(__fmul_rn(y, x), 5.0000001201E-1f);
  y = __fadd_rn(__fmul_rn(y, z), x);
  y = __fadd_rn(y, 1.0f);
  int n = __float2int_rz(fx);              // fx is integral
  float p2n = __int_as_float((n + 127) << 23);
  return __fmul_rn(y, p2n);
}

// numpy pairwise_sum structure for n=64 (unrolled-by-8 C loop); row-uniform
// by commutativity. Verified round 6. DO NOT TOUCH.
static __device__ __forceinline__ float np_pairwise_sum64(float x, int lane) {
  int k = lane & 7;
  float r = __shfl(x, k);
  #pragma unroll
  for (int i2 = 1; i2 < 8; ++i2) r = __fadd_rn(r, __shfl(x, k + 8 * i2));
  float u = __fadd_rn(r, __shfl_xor(r, 1));
  float v = __fadd_rn(u, __shfl_xor(u, 2));
  float w = __fadd_rn(v, __shfl_xor(v, 4));
  return w;
}

// np einsum dot emulation, packed-f32 form. Mathematically IDENTICAL ops in
// IDENTICAL order to the verified round-6 scalar version: acc_j (j = d mod 4)
// chains with separate mul/add (contract OFF), finalize (a0+a2)+(a1+a3).
// f32x2 lanes: A01=(acc0,acc1), A23=(acc2,acc3) -> v_pk_mul/v_pk_add.
static __device__ __forceinline__ float np_dot32(const float4* __restrict__ q4,
                                                 const float* __restrict__ krow,
                                                 float scale) {
#pragma clang fp contract(off)
  const f32x2* k2 = (const f32x2*)krow;   // 8B-aligned (KSTR even)
  f32x2 sc; sc.x = scale; sc.y = scale;
  f32x2 A01; A01.x = 0.0f; A01.y = 0.0f;
  f32x2 A23; A23.x = 0.0f; A23.y = 0.0f;
  #pragma unroll
  for (int i4 = 0; i4 < 8; ++i4) {
    float4 q = q4[i4];
    f32x2 q01; q01.x = q.x; q01.y = q.y;
    f32x2 q23; q23.x = q.z; q23.y = q.w;
    A01 = A01 + (q01 * sc) * k2[2 * i4];
    A23 = A23 + (q23 * sc) * k2[2 * i4 + 1];
  }
  f32x2 R = A01 + A23;                    // (acc0+acc2, acc1+acc3)
  return __fadd_rn(R.x, R.y);
}

// Kernel 1: one block per (window, head, half). 512 threads = 8 waves; each
// wave owns 16 consecutive query rows, NO per-row block barriers. K and V in
// LDS (stride 34). Gather chain pipelined 3 rows deep:
//   kidx[r+3],pv[r+3] issued at row r start; rpi[r+2] at row r start (its
//   kidx is a full row old); bias[r+2] post-softmax (rpi ~0.5 row old);
//   bias[r] consumed at row r dot-end (~1.5 rows after issue).
// Rank via u64 keys (value||63-lane): stable descending rank, ties -> lower
// slot, identical rule to round 6. Selection via ds_permute (ranks are a
// permutation of 0..63) -> coalesced vals/idx writes + b128 sel reads.
__global__ __launch_bounds__(512, 4) void attn_topk_kernel(
    const float* __restrict__ qkvp,        // [NW, NTOK, 4*CDIM]
    const float* __restrict__ pfa_values,  // [NW, NH, NTOK, TKIN]
    const int*   __restrict__ pfa_indices, // [NW, NH, NTOK, TKIN]
    const int*   __restrict__ rpi,         // [NTOK, NTOK]
    const float* __restrict__ bias_table,  // [961, NH]
    float* __restrict__ xattn,             // [NW*NTOK, CDIM] (pre-projection, = out region)
    float* __restrict__ vals_out,          // [NW, NH, NTOK, TKOUT]
    float* __restrict__ idx_out)           // [NW, NH, NTOK, TKOUT] (as floats)
{
  __shared__ __align__(16) float k_s[NTOK * KSTR];
  __shared__ __align__(16) float v_s[NTOK * KSTR];
  __shared__ __align__(16) unsigned long long key_buf[8 * 64];
  __shared__ __align__(16) float sel_val[8 * 32];
  __shared__ __align__(16) int   sel_idx[8 * 32];

  const int bx    = blockIdx.x;            // 0..511
  const int b     = bx >> 3;
  const int h     = (bx >> 1) & 3;
  const int qhalf = bx & 1;
  const int tid   = threadIdx.x;
  const int lane  = tid & 63;
  const int wid   = tid >> 6;              // 0..7

  const float SCALE_F = 0.17677669529663687f;  // fl32(32^-0.5)
  const float EPS_F   = 1e-10f;

  const float* qbase = qkvp + (size_t)b * (NTOK * 4 * CDIM);

  // Stage K (part 1) and V (part 2) for this (b,h): 256 tokens x 32 dims.
  #pragma unroll 4
  for (int l = 0; l < 16; ++l) {
    int e   = l * 512 + tid;
    int tok = e >> 5, d = e & 31;
    int g   = tok * 512 + h * 32 + d;
    k_s[tok * KSTR + d] = qbase[g + 128];
    v_s[tok * KSTR + d] = qbase[g + 256];
  }
  __syncthreads();

  const int i0 = qhalf * 128 + wid * 16;   // this wave's first row
  const size_t rowbase = (size_t)((b * NH + h) * NTOK + i0);
  const int*   idx_p = pfa_indices + rowbase * TKIN + lane;
  const float* val_p = pfa_values  + rowbase * TKIN + lane;

  // Prologue: fill the 3-deep pipeline (rows 0,1,2 kidx/pv; rpi/bias 0,1)
  int   kx0 = idx_p[0],        kx1 = idx_p[TKIN],      kx2 = idx_p[2 * TKIN];
  float pv0 = val_p[0],        pv1 = val_p[TKIN],      pv2 = val_p[2 * TKIN];
  int   rp0 = rpi[(i0 + 0) * NTOK + kx0];
  int   rp1 = rpi[(i0 + 1) * NTOK + kx1];
  float bi0 = bias_table[rp0 * NH + h];
  float bi1 = bias_table[rp1 * NH + h];
  float4 qv[8];
  #pragma unroll
  for (int u = 0; u < 8; ++u)
    qv[u] = ((const float4*)(qbase + i0 * 512 + h * 32))[u];

  for (int r = 0; r < 16; ++r) {
    const int i = i0 + r;
    const size_t rowoff = rowbase + r;
    const int r1 = (r + 1 < 16) ? r + 1 : 15;
    const int r2 = (r + 2 < 16) ? r + 2 : 15;
    const int r3 = (r + 3 < 16) ? r + 3 : 15;

    // ---- pipeline issues: independents + aged-dependency links
    const int   kx3  = idx_p[r3 * TKIN];
    const float pv3  = val_p[r3 * TKIN];
    const int   rp2  = rpi[(i0 + r2) * NTOK + kx2];    // kx2 is 1 row old
    float4 qn[8];
    #pragma unroll
    for (int u = 0; u < 8; ++u)
      qn[u] = ((const float4*)(qbase + (i0 + r1) * 512 + h * 32))[u];
    const float lepe = qbase[i * 512 + 384 + h * 32 + (lane & 31)];

    // QK dot (bit-exact np einsum emulation, packed form)
    const float dot = np_dot32(qv, &k_s[kx0 * KSTR], SCALE_F);
    const float s   = __fadd_rn(dot, bi0);

    // softmax over the 64 keys (one per lane); np-structured sums
    float m  = wave_max64f(s);
    float ex = cephes_expf(__fsub_rn(s, m));
    float sm = np_pairwise_sum64(ex, lane);
    float p0 = __fdiv_rn(ex, sm);
    float a  = __fmul_rn(p0, pv0);             // modulate by prior values
    float s2 = np_pairwise_sum64(a, lane);
    float af = __fdiv_rn(__fadd_rn(a, EPS_F), __fadd_rn(s2, EPS_F));

    // issue bias[r+2] now (rp2 issued ~500cyc ago; consumed in ~1.5 rows)
    const float bi2 = bias_table[rp2 * NH + h];

    // stable descending rank via u64 keys: (af_bits<<32)|(63-lane).
    // pack_j > pack_me with equal af  <=>  j < me  (ties -> lower slot).
    const unsigned long long kme =
        ((unsigned long long)__float_as_uint(af) << 32) | (unsigned)(63 - lane);
    key_buf[wid * 64 + lane] = kme;
    int rank = 0;
    const ulonglong2* kb2 = (const ulonglong2*)&key_buf[wid * 64];
    #pragma unroll
    for (int j2 = 0; j2 < 32; ++j2) {
      ulonglong2 kk = kb2[j2];
      rank += (kk.x > kme) ? 1 : 0;
      rank += (kk.y > kme) ? 1 : 0;
    }

    // selection: ranks are a permutation of 0..63 -> push to lane=rank
    float selv = __uint_as_float(
        __builtin_amdgcn_ds_permute(rank << 2, __float_as_uint(af)));
    int   seli = __builtin_amdgcn_ds_permute(rank << 2, kx0);
    if (lane < TKOUT) {
      vals_out[rowoff * TKOUT + lane] = selv;         // coalesced
      idx_out [rowoff * TKOUT + lane] = (float)seli;  // coalesced
      sel_val[wid * 32 + lane] = selv;
      sel_idx[wid * 32 + lane] = seli;
    }

    // AV: lanes (ph,d); sel via b128 broadcasts; fmaf (tolerance region)
    const int ph = lane >> 5, d = lane & 31;
    const float4* sv4 = (const float4*)&sel_val[wid * 32 + ph * 16];
    const int4*   si4 = (const int4*)  &sel_idx[wid * 32 + ph * 16];
    float oacc = 0.0f;
    #pragma unroll
    for (int g = 0; g < 4; ++g) {
      float4 vv = sv4[g];
      int4   ii = si4[g];
      oacc = fmaf(vv.x, v_s[ii.x * KSTR + d], oacc);
      oacc = fmaf(vv.y, v_s[ii.y * KSTR + d], oacc);
      oacc = fmaf(vv.z, v_s[ii.z * KSTR + d], oacc);
      oacc = fmaf(vv.w, v_s[ii.w * KSTR + d], oacc);
    }
    oacc += __shfl_xor(oacc, 32);
    if (ph == 0) {
      xattn[(size_t)(b * NTOK + i) * CDIM + h * 32 + d] = oacc + lepe;
    }

    // rotate pipeline registers
    kx0 = kx1; kx1 = kx2; kx2 = kx3;
    pv0 = pv1; pv1 = pv2; pv2 = pv3;
    bi0 = bi1; bi1 = bi2;
    #pragma unroll
    for (int u = 0; u < 8; ++u) qv[u] = qn[u];
  }
}

// Kernel 2: in-place projection out = x @ W^T + b over 16 rows per block.
// Each block stages exactly its own 16 rows before overwriting them.
__global__ __launch_bounds__(256) void proj_kernel(
    float* __restrict__ x_out,            // [NW*NTOK, CDIM], read then overwritten
    const float* __restrict__ proj_w,     // [CDIM, CDIM]  (out_c, in_c)
    const float* __restrict__ proj_b)     // [CDIM]
{
  __shared__ __align__(16) float w_t[CDIM * 132];   // w_t[ic][oc], stride 132
  __shared__ __align__(16) float x_s[16 * CDIM];

  const int tid = threadIdx.x;
  const int rowbase = blockIdx.x * 16;

  #pragma unroll 8
  for (int l = 0; l < 64; ++l) {
    int e  = l * 256 + tid;
    int oc = e >> 7, ic = e & 127;
    w_t[ic * 132 + oc] = proj_w[e];
  }
  #pragma unroll
  for (int l = 0; l < 8; ++l) {
    int e = l * 256 + tid;
    x_s[e] = x_out[(size_t)rowbase * CDIM + e];
  }
  __syncthreads();

  const int c0 = tid & 31;   // column group (4 cols)
  const int rs = tid >> 5;   // row slot (rows rs and rs+8)

  float acc0x = 0, acc0y = 0, acc0z = 0, acc0w = 0;
  float acc1x = 0, acc1y = 0, acc1z = 0, acc1w = 0;

  for (int cc4 = 0; cc4 < 32; ++cc4) {
    float4 x0 = *(const float4*)&x_s[rs * CDIM + cc4 * 4];
    float4 x1 = *(const float4*)&x_s[(rs + 8) * CDIM + cc4 * 4];
    const float xs0[4] = {x0.x, x0.y, x0.z, x0.w};
    const float xs1[4] = {x1.x, x1.y, x1.z, x1.w};
    #pragma unroll
    for (int u = 0; u < 4; ++u) {
      int cc = cc4 * 4 + u;
      float4 w4 = *(const float4*)&w_t[cc * 132 + c0 * 4];
      acc0x += xs0[u] * w4.x;  acc0y += xs0[u] * w4.y;
      acc0z += xs0[u] * w4.z;  acc0w += xs0[u] * w4.w;
      acc1x += xs1[u] * w4.x;  acc1y += xs1[u] * w4.y;
      acc1z += xs1[u] * w4.z;  acc1w += xs1[u] * w4.w;
    }
  }

  float4 bb = *(const float4*)&proj_b[c0 * 4];
  float4 o0 = make_float4(acc0x + bb.x, acc0y + bb.y, acc0z + bb.z, acc0w + bb.w);
  float4 o1 = make_float4(acc1x + bb.x, acc1y + bb.y, acc1z + bb.z, acc1w + bb.w);
  *(float4*)&x_out[(size_t)(rowbase + rs) * CDIM + c0 * 4] = o0;
  *(float4*)&x_out[(size_t)(rowbase + rs + 8) * CDIM + c0 * 4] = o1;
}

extern "C" void kernel_launch(void* const* d_in, const int* in_sizes, int n_in,
                              void* d_out, int out_size, void* d_ws, size_t ws_size,
                              hipStream_t stream) {
  (void)in_sizes; (void)n_in; (void)d_ws; (void)ws_size; (void)out_size;

  const float* qkvp        = (const float*)d_in[0];
  const float* pfa_values  = (const float*)d_in[1];
  const int*   pfa_indices = (const int*)  d_in[2];
  const int*   rpi         = (const int*)  d_in[3];
  const float* bias_table  = (const float*)d_in[4];
  const float* proj_w      = (const float*)d_in[5];
  const float* proj_b      = (const float*)d_in[6];

  float* out      = (float*)d_out;                       // [NW*NTOK, CDIM]
  float* vals_out = out + (size_t)NW * NTOK * CDIM;      // [NW,NH,NTOK,TKOUT]
  float* idx_out  = vals_out + (size_t)NW * NH * NTOK * TKOUT;

  // Kernel 1 writes pre-projection xattn into the `out` region (same size),
  // plus vals/new_idx. Kernel 2 projects in place.
  attn_topk_kernel<<<NW * NH * 2, 512, 0, stream>>>(
      qkvp, pfa_values, pfa_indices, rpi, bias_table, out, vals_out, idx_out);
  proj_kernel<<<(NW * NTOK) / 16, 256, 0, stream>>>(out, proj_w, proj_b);
}